// Round 11
// baseline (737.237 us; speedup 1.0000x reference)
//
#include <hip/hip_runtime.h>
#include <stdint.h>

typedef unsigned short u16;
typedef __attribute__((ext_vector_type(8))) short bf16x8;
typedef __attribute__((ext_vector_type(4))) float f32x4;

#define NB    65536
#define DDIM  64
#define HDIM  1024
#define EDIM  1024

__device__ __forceinline__ float bf2f(u16 u) {
  return __uint_as_float(((unsigned)u) << 16);
}
__device__ __forceinline__ u16 f2bf(float f) {
  unsigned u = __float_as_uint(f);
  unsigned r = ((u >> 16) & 1u) + 0x7FFFu;
  return (u16)((u + r) >> 16);
}
__device__ __forceinline__ float siluf(float x) { return x / (1.0f + __expf(-x)); }

#if defined(__has_builtin)
#  if __has_builtin(__builtin_amdgcn_global_load_lds)
#    define GLL_OK 1
#  endif
#endif
#ifndef GLL_OK
#  define GLL_OK 0
#endif

__device__ __forceinline__ void gll16(const void* g, void* lds_base, int lane) {
#if GLL_OK
  (void)lane;
  __builtin_amdgcn_global_load_lds((const __attribute__((address_space(1))) void*)g,
                                   (__attribute__((address_space(3))) void*)lds_base,
                                   16, 0, 0);
#else
  *(uint4*)((char*)lds_base + lane * 16) = *(const uint4*)g;
#endif
}

// ---------------------------------------------------------------------------
// fp32 -> bf16 transposed weight convert: W (K x N) -> WT (N x K)
// ---------------------------------------------------------------------------
__global__ __launch_bounds__(256) void convtrans(const float* __restrict__ W,
                                                 u16* __restrict__ WT, int K, int N) {
  __shared__ float tile[32][33];
  const int tx = threadIdx.x & 31;
  const int ty = threadIdx.x >> 5;
  const int n0 = blockIdx.x * 32;
  const int k0 = blockIdx.y * 32;
#pragma unroll
  for (int i = 0; i < 4; ++i) {
    const int k = ty + i * 8;
    tile[k][tx] = W[(long)(k0 + k) * N + n0 + tx];
  }
  __syncthreads();
#pragma unroll
  for (int i = 0; i < 4; ++i) {
    const int n = ty + i * 8;
    WT[(long)(n0 + n) * K + k0 + tx] = f2bf(tile[tx][n]);
  }
}

// ---------------------------------------------------------------------------
// te2 at the 4 Chebyshev nodes
// ---------------------------------------------------------------------------
__global__ __launch_bounds__(256) void te_nodes(const float* __restrict__ Wt1,
                                                const float* __restrict__ bt1,
                                                const float* __restrict__ Wt2,
                                                const float* __restrict__ bt2,
                                                float* __restrict__ te2n) {
  const float tnodes[4] = {0.96193976625564337f, 0.69134171618254492f,
                           0.30865828381745508f, 0.03806023374435663f};
  const int j = blockIdx.x;
  const float tj = tnodes[j];
  __shared__ float te1[1024];
  const int tid = threadIdx.x;
  for (int e = tid; e < 1024; e += 256) te1[e] = siluf(tj * Wt1[e] + bt1[e]);
  __syncthreads();
  float a0 = bt2[tid], a1 = bt2[tid + 256], a2 = bt2[tid + 512], a3 = bt2[tid + 768];
  for (int e = 0; e < 1024; ++e) {
    const float v = te1[e];
    const float* w = Wt2 + (long)e * 1024;
    a0 += v * w[tid];
    a1 += v * w[tid + 256];
    a2 += v * w[tid + 512];
    a3 += v * w[tid + 768];
  }
  te2n[j * 1024 + tid]       = siluf(a0);
  te2n[j * 1024 + tid + 256] = siluf(a1);
  te2n[j * 1024 + tid + 512] = siluf(a2);
  te2n[j * 1024 + tid + 768] = siluf(a3);
}

// ---------------------------------------------------------------------------
// ss node values: F[(b*4+j)*2048 + i] = (te2n[j] @ Ws_b + bs_b)[i]
// ---------------------------------------------------------------------------
__global__ __launch_bounds__(256) void ss_nodes(const float* __restrict__ te2n,
                                                const float* __restrict__ Ws1,
                                                const float* __restrict__ bs1,
                                                const float* __restrict__ Ws2,
                                                const float* __restrict__ bs2,
                                                const float* __restrict__ Ws3,
                                                const float* __restrict__ bs3,
                                                float* __restrict__ F) {
  const int i = blockIdx.x * 256 + threadIdx.x;
  const int j = blockIdx.y;
  const int b = blockIdx.z;
  const float* Ws = (b == 0) ? Ws1 : (b == 1) ? Ws2 : Ws3;
  const float* bs = (b == 0) ? bs1 : (b == 1) ? bs2 : bs3;
  const float* te = te2n + j * 1024;
  float acc = bs[i];
  for (int k = 0; k < 1024; ++k) acc += te[k] * Ws[(long)k * 2048 + i];
  F[(b * 4 + j) * 2048 + i] = acc;
}

// ---------------------------------------------------------------------------
// gemm_g1: G1 with FUSED mixed-input staging (r10, unchanged).
// ---------------------------------------------------------------------------
__global__ __launch_bounds__(256) void gemm_g1(const float* __restrict__ gt,
                                               const float* __restrict__ noise,
                                               const float* __restrict__ t,
                                               const u16* __restrict__ BT,
                                               const float* __restrict__ bias,
                                               u16* __restrict__ Cb,
                                               float* __restrict__ SP) {
  __shared__ u16 lA[128 * 64];
  __shared__ u16 lB[128 * 64];
  const int tid = threadIdx.x;
  const int lane = tid & 63;
  const int wid = tid >> 6;

  int mtile, ntile;
  if (gridDim.x == 8 && (gridDim.y & 7) == 0) {
    const int g = (int)blockIdx.x + ((int)blockIdx.y << 3);
    mtile = ((g >> 6) << 3) + (g & 7);
    ntile = (g >> 3) & 7;
  } else {
    ntile = blockIdx.x;
    mtile = blockIdx.y;
  }
  const long m0 = (long)mtile * 128;
  const int n0 = ntile * 128;
  const int wm = (wid >> 1) * 64;
  const int wn = (wid & 1) * 64;

  const int fr = lane & 15;
  const int kq = lane >> 4;

#pragma unroll
  for (int c = 0; c < 4; ++c) {
    const int u = c * 256 + tid;
    const int row = u >> 3;
    const int src = (u & 7) ^ (row & 7);
    gll16(BT + (size_t)(n0 + row) * 64 + src * 8, &lB[(c * 256 + wid * 64) * 8], lane);
  }
#pragma unroll
  for (int c = 0; c < 4; ++c) {
    const int u = c * 256 + tid;
    const int row = u >> 3;
    const int src = (u & 7) ^ (row & 7);
    const long gr = m0 + row;
    const float tv = t[gr];
    const float one_m = 1.0f - tv;
    const float4 ga = *(const float4*)&gt[gr * 64 + src * 8];
    const float4 gb = *(const float4*)&gt[gr * 64 + src * 8 + 4];
    const float4 na = *(const float4*)&noise[gr * 64 + src * 8];
    const float4 nb = *(const float4*)&noise[gr * 64 + src * 8 + 4];
    ushort4 o0, o1;
    o0.x = f2bf(tv * ga.x + one_m * na.x);
    o0.y = f2bf(tv * ga.y + one_m * na.y);
    o0.z = f2bf(tv * ga.z + one_m * na.z);
    o0.w = f2bf(tv * ga.w + one_m * na.w);
    o1.x = f2bf(tv * gb.x + one_m * nb.x);
    o1.y = f2bf(tv * gb.y + one_m * nb.y);
    o1.z = f2bf(tv * gb.z + one_m * nb.z);
    o1.w = f2bf(tv * gb.w + one_m * nb.w);
    *(ushort4*)&lA[u * 8] = o0;
    *(ushort4*)&lA[u * 8 + 4] = o1;
  }
  __syncthreads();

  f32x4 acc[4][4];
  const f32x4 z = {0.f, 0.f, 0.f, 0.f};
#pragma unroll
  for (int i = 0; i < 4; ++i)
#pragma unroll
    for (int j = 0; j < 4; ++j) acc[i][j] = z;

#pragma unroll
  for (int ks = 0; ks < 2; ++ks) {
    bf16x8 af[4], bq[4];
#pragma unroll
    for (int i = 0; i < 4; ++i) {
      const int row = wm + i * 16 + fr;
      const int slot = (ks * 4 + kq) ^ (row & 7);
      af[i] = *(const bf16x8*)&lA[row * 64 + slot * 8];
    }
#pragma unroll
    for (int j = 0; j < 4; ++j) {
      const int row = wn + j * 16 + fr;
      const int slot = (ks * 4 + kq) ^ (row & 7);
      bq[j] = *(const bf16x8*)&lB[row * 64 + slot * 8];
    }
#pragma unroll
    for (int i = 0; i < 4; ++i)
#pragma unroll
      for (int j = 0; j < 4; ++j)
        acc[i][j] =
            __builtin_amdgcn_mfma_f32_16x16x32_bf16(af[i], bq[j], acc[i][j], 0, 0, 0);
  }

  const int rr = kq * 4;
  float bj[4];
#pragma unroll
  for (int j = 0; j < 4; ++j) bj[j] = bias[n0 + wn + j * 16 + fr];
#pragma unroll
  for (int j = 0; j < 4; ++j) {
    const int gn = n0 + wn + j * 16 + fr;
#pragma unroll
    for (int i = 0; i < 4; ++i) {
      const long gm = m0 + wm + i * 16 + rr;
#pragma unroll
      for (int r = 0; r < 4; ++r) Cb[(gm + r) * 1024 + gn] = f2bf(acc[i][j][r] + bj[j]);
    }
  }
  const int slice = ntile * 2 + (wid & 1);
#pragma unroll
  for (int i = 0; i < 4; ++i) {
#pragma unroll
    for (int r = 0; r < 4; ++r) {
      float s = 0.f, q = 0.f;
#pragma unroll
      for (int j = 0; j < 4; ++j) {
        const float v = acc[i][j][r] + bj[j];
        s += v;
        q += v * v;
      }
#pragma unroll
      for (int m = 1; m < 16; m <<= 1) {
        s += __shfl_xor(s, m, 64);
        q += __shfl_xor(q, m, 64);
      }
      if (fr == 0) {
        const long row = m0 + wm + i * 16 + rr + r;
        float2 st;
        st.x = s;
        st.y = q;
        *(float2*)&SP[(row * 16 + slice) * 2] = st;
      }
    }
  }
}

// ---------------------------------------------------------------------------
// gemm16: 256x256 MFMA GEMM (N=K=1024), 1024 threads = 16 waves (4M x 4N,
// per-wave 64x64, acc=64 AGPR).  4 waves/SIMD: doubles wave-level latency
// hiding vs all r5-r9 variants (which all ran 2/SIMD — the plateau invariant).
// Per K-64 tile, 2 phases:
//   P0: stage A0',B0'(t+1) [1 gll16 ea]; vmcnt(2) retires tile t (4 halves
//       issued across t-1's phases); BarA; 8 ds_read (ks=0); 16 MFMA.
//   P1: stage A1',B1'(t+1); 8 ds_read (ks=1); BarB (WAR release); 16 MFMA.
// LDS 128 KiB dbuf, XOR-swizzle (16B slot ^= row&7) via pre-swizzled source.
// Epilogue: bf16 C + per-row (sum,sumsq) slice partials (16 slices).
// XCD-affinity: mtile%8 == linear-bid%8 when gridDim.y%8==0.
// ---------------------------------------------------------------------------
__global__ __launch_bounds__(1024) void gemm16(const u16* __restrict__ A,
                                               const u16* __restrict__ BT,
                                               const float* __restrict__ bias,
                                               u16* __restrict__ C,
                                               float* __restrict__ SP) {
  __shared__ u16 L[65536];
  const int tid = threadIdx.x;
  const int lane = tid & 63;
  const int wid = tid >> 6;  // 0..15

  int mtile, ntile;
  if ((gridDim.y & 7) == 0) {
    const int g = (int)blockIdx.x + ((int)blockIdx.y << 2);
    mtile = ((g >> 5) << 3) | (g & 7);
    ntile = (g >> 3) & 3;
  } else {
    ntile = blockIdx.x;
    mtile = blockIdx.y;
  }
  const long m0 = (long)mtile * 256;
  const int n0 = ntile * 256;
  const int mwoff = (wid >> 2) * 64;
  const int nwoff = (wid & 3) * 64;

  const u16* Ag = A + m0 * 1024;
  const u16* Bg = BT + (long)n0 * 1024;

  const int fr = lane & 15;
  const int kq = lane >> 4;

  // staging: half-tile (128 rows x 64 k = 16 KB) = 1 gll16/thread.
  // unit u = tid: row = u>>3 (0..127), lds slot = u&7, source slot pre-swizzled.
  const int srow = tid >> 3;
  const int ssrc = (tid & 7) ^ (srow & 7);
  auto stA = [&](int buf, int h, int kt) {
    gll16(Ag + (size_t)(h * 128 + srow) * 1024 + kt * 64 + ssrc * 8,
          &L[buf * 16384 + h * 8192 + wid * 512], lane);
  };
  auto stB = [&](int buf, int h, int kt) {
    gll16(Bg + (size_t)(h * 128 + srow) * 1024 + kt * 64 + ssrc * 8,
          &L[32768 + buf * 16384 + h * 8192 + wid * 512], lane);
  };

  f32x4 acc[4][4];
  const f32x4 z = {0.f, 0.f, 0.f, 0.f};
#pragma unroll
  for (int i = 0; i < 4; ++i)
#pragma unroll
    for (int j = 0; j < 4; ++j) acc[i][j] = z;

  bf16x8 af[4], bq[4];

#define RD(buf, ks)                                                                  \
  _Pragma("unroll") for (int i = 0; i < 4; ++i) {                                    \
    const int row = mwoff + i * 16 + fr;                                             \
    const int slot = ((ks)*4 + kq) ^ (row & 7);                                      \
    af[i] = *(const bf16x8*)&L[(buf)*16384 + row * 64 + slot * 8];                   \
  }                                                                                  \
  _Pragma("unroll") for (int j = 0; j < 4; ++j) {                                    \
    const int row = nwoff + j * 16 + fr;                                             \
    const int slot = ((ks)*4 + kq) ^ (row & 7);                                      \
    bq[j] = *(const bf16x8*)&L[32768 + (buf)*16384 + row * 64 + slot * 8];           \
  }
#define VMW(n) asm volatile("s_waitcnt vmcnt(" #n ")" ::: "memory");
#define BARS()                             \
  asm volatile("s_barrier" ::: "memory");  \
  __builtin_amdgcn_sched_barrier(0);
#define MFMA16V()                                                                    \
  __builtin_amdgcn_s_setprio(1);                                                     \
  _Pragma("unroll") for (int i = 0; i < 4; ++i) _Pragma("unroll")                    \
      for (int j = 0; j < 4; ++j) {                                                  \
    acc[i][j] = __builtin_amdgcn_mfma_f32_16x16x32_bf16(af[i], bq[j], acc[i][j],     \
                                                        0, 0, 0);                    \
  }                                                                                  \
  __builtin_amdgcn_s_setprio(0);

  // prologue: stage tile 0 fully; drain; barrier
  stA(0, 0, 0);
  stB(0, 0, 0);
  stA(0, 1, 0);
  stB(0, 1, 0);
  VMW(0)
  BARS()

  // steady tiles 0..14 (stage tile t+1)
  for (int kt = 0; kt < 15; ++kt) {
    const int c = kt & 1;
    const int nx = c ^ 1;
    const int kn = kt + 1;
    // P0
    stA(nx, 0, kn);
    stB(nx, 0, kn);
    VMW(2)   // retires all 4 halves of tile t (kt=0: trivially satisfied)
    BARS()
    RD(c, 0)
    MFMA16V()
    // P1
    stA(nx, 1, kn);
    stB(nx, 1, kn);
    RD(c, 1)
    BARS()   // WAR release: reads of buf c done before next P0's stages
    MFMA16V()
  }
  // tail tile 15 (buf 1, no staging)
  VMW(0)
  BARS()
  RD(1, 0)
  MFMA16V()
  RD(1, 1)
  MFMA16V()

#undef RD
#undef VMW
#undef BARS
#undef MFMA16V

  // epilogue: C = bf16(acc+bias); per-row (sum,sumsq) over this wave's 64 cols
  float bj[4];
#pragma unroll
  for (int j = 0; j < 4; ++j) bj[j] = bias[n0 + nwoff + j * 16 + fr];
  const int slice = ntile * 4 + (wid & 3);
#pragma unroll
  for (int i = 0; i < 4; ++i) {
    const long gmb = m0 + mwoff + i * 16 + kq * 4;
#pragma unroll
    for (int j = 0; j < 4; ++j) {
      const int gn = n0 + nwoff + j * 16 + fr;
#pragma unroll
      for (int r = 0; r < 4; ++r) C[(gmb + r) * 1024 + gn] = f2bf(acc[i][j][r] + bj[j]);
    }
#pragma unroll
    for (int r = 0; r < 4; ++r) {
      float s = 0.f, q = 0.f;
#pragma unroll
      for (int j = 0; j < 4; ++j) {
        const float v = acc[i][j][r] + bj[j];
        s += v;
        q += v * v;
      }
#pragma unroll
      for (int m = 1; m < 16; m <<= 1) {
        s += __shfl_xor(s, m, 64);
        q += __shfl_xor(q, m, 64);
      }
      if (fr == 0) {
        float2 st;
        st.x = s;
        st.y = q;
        *(float2*)&SP[((gmb + r) * 16 + slice) * 2] = st;
      }
    }
  }
}

// ---------------------------------------------------------------------------
// gemm_fin: final 128-col GEMM, conflict-free swizzled (r10, unchanged).
// ---------------------------------------------------------------------------
__global__ __launch_bounds__(256) void gemm_fin(const u16* __restrict__ A,
                                                const u16* __restrict__ BT, int K,
                                                const float* __restrict__ bias0,
                                                const float* __restrict__ bias1,
                                                float* __restrict__ Cf0,
                                                float* __restrict__ Cf1) {
  __shared__ u16 lA[128 * 64];
  __shared__ u16 lB[128 * 64];
  const int tid = threadIdx.x;
  const int lane = tid & 63;
  const int wid = tid >> 6;
  const long m0 = (long)blockIdx.y * 128;
  const int n0 = 0;
  const int wm = (wid >> 1) * 64;
  const int wn = (wid & 1) * 64;

  const u16* Ab = A + m0 * K;
  const u16* Bb = BT;

  const int fr = lane & 15;
  const int kq = lane >> 4;

  f32x4 acc[4][4];
  const f32x4 z = {0.f, 0.f, 0.f, 0.f};
#pragma unroll
  for (int i = 0; i < 4; ++i)
#pragma unroll
    for (int j = 0; j < 4; ++j) acc[i][j] = z;

  for (int kk = 0; kk < K; kk += 64) {
#pragma unroll
    for (int c = 0; c < 4; ++c) {
      const int u = c * 256 + tid;
      const int row = u >> 3;
      const int src = (u & 7) ^ (row & 7);
      gll16(Ab + (size_t)row * K + kk + src * 8, &lA[(c * 256 + wid * 64) * 8], lane);
      gll16(Bb + (size_t)row * K + kk + src * 8, &lB[(c * 256 + wid * 64) * 8], lane);
    }
    __syncthreads();
#pragma unroll
    for (int ks = 0; ks < 2; ++ks) {
      bf16x8 af[4], bq[4];
#pragma unroll
      for (int i = 0; i < 4; ++i) {
        const int row = wm + i * 16 + fr;
        const int slot = (ks * 4 + kq) ^ (row & 7);
        af[i] = *(const bf16x8*)&lA[row * 64 + slot * 8];
      }
#pragma unroll
      for (int j = 0; j < 4; ++j) {
        const int row = wn + j * 16 + fr;
        const int slot = (ks * 4 + kq) ^ (row & 7);
        bq[j] = *(const bf16x8*)&lB[row * 64 + slot * 8];
      }
#pragma unroll
      for (int i = 0; i < 4; ++i)
#pragma unroll
        for (int j = 0; j < 4; ++j)
          acc[i][j] =
              __builtin_amdgcn_mfma_f32_16x16x32_bf16(af[i], bq[j], acc[i][j], 0, 0, 0);
    }
    __syncthreads();
  }

  const int rr = kq * 4;
#pragma unroll
  for (int j = 0; j < 4; ++j) {
    const int gn = n0 + wn + j * 16 + fr;
    const float bv = (gn < 64) ? bias0[gn] : bias1[gn - 64];
    float* dst = (gn < 64) ? (Cf0 + gn) : (Cf1 + (gn - 64));
#pragma unroll
    for (int i = 0; i < 4; ++i) {
      const long gm = m0 + wm + i * 16 + rr;
#pragma unroll
      for (int r = 0; r < 4; ++r) dst[(gm + r) * 64] = acc[i][j][r] + bv;
    }
  }
}

// ---------------------------------------------------------------------------
// stats_fin: SP[row][16][2] -> ST[row][8] = {mu, rstd, L0, L1, L2, L3, 0, 0}
// ---------------------------------------------------------------------------
__global__ __launch_bounds__(256) void stats_fin(const float* __restrict__ SP,
                                                 const float* __restrict__ t,
                                                 float* __restrict__ ST, int nrows) {
  const int row = blockIdx.x * 256 + threadIdx.x;
  if (row >= nrows) return;
  float S = 0.f, Q = 0.f;
#pragma unroll
  for (int i = 0; i < 16; ++i) {
    const float2 v = *(const float2*)&SP[row * 32 + i * 2];
    S += v.x;
    Q += v.y;
  }
  const float mu = S * (1.0f / 1024.0f);
  const float var = Q * (1.0f / 1024.0f) - mu * mu;
  const float rstd = rsqrtf(var + 1e-5f);
  const float tv = t[row];
  const float tn0 = 0.96193976625564337f, tn1 = 0.69134171618254492f,
              tn2 = 0.30865828381745508f, tn3 = 0.03806023374435663f;
  float4 a, b;
  a.x = mu;
  a.y = rstd;
  a.z = (tv - tn1) * (tv - tn2) * (tv - tn3) * 6.1229347f;
  a.w = (tv - tn0) * (tv - tn2) * (tv - tn3) * -14.7820730f;
  b.x = (tv - tn0) * (tv - tn1) * (tv - tn3) * 14.7820730f;
  b.y = (tv - tn0) * (tv - tn1) * (tv - tn2) * -6.1229347f;
  b.z = 0.f;
  b.w = 0.f;
  *(float4*)&ST[row * 8] = a;
  *(float4*)&ST[row * 8 + 4] = b;
}

// ---------------------------------------------------------------------------
// ln_apply2: IN-PLACE LN + adaLN modulate + silu; per-row params from ST.
// ---------------------------------------------------------------------------
__global__ __launch_bounds__(256) void ln_apply2(u16* __restrict__ buf,
                                                 const float* __restrict__ gamma,
                                                 const float* __restrict__ beta,
                                                 const float* __restrict__ Fb,  // [4][2048]
                                                 const float* __restrict__ ST,
                                                 int nrows) {
  const int tid = threadIdx.x;
  const int col = tid * 4;

  float Fs[4][4], Fh[4][4];
#pragma unroll
  for (int j = 0; j < 4; ++j)
#pragma unroll
    for (int c = 0; c < 4; ++c) {
      Fs[j][c] = Fb[j * 2048 + col + c];
      Fh[j][c] = Fb[j * 2048 + 1024 + col + c];
    }
  const float4 gv = *(const float4*)&gamma[col];
  const float4 bv = *(const float4*)&beta[col];
  const float g[4] = {gv.x, gv.y, gv.z, gv.w};
  const float be[4] = {bv.x, bv.y, bv.z, bv.w};

  for (long row = blockIdx.x; row < nrows; row += gridDim.x) {
    const float4 p0 = *(const float4*)&ST[row * 8];
    const float4 p1 = *(const float4*)&ST[row * 8 + 4];
    const float mu = p0.x, rstd = p0.y;
    const float L0 = p0.z, L1 = p0.w, L2 = p1.x, L3 = p1.y;

    const ushort4 hv = *(const ushort4*)&buf[row * 1024 + col];
    const float x[4] = {bf2f(hv.x), bf2f(hv.y), bf2f(hv.z), bf2f(hv.w)};
    float o[4];
#pragma unroll
    for (int c = 0; c < 4; ++c) {
      const float xn = (x[c] - mu) * rstd * g[c] + be[c];
      const float sc = L0 * Fs[0][c] + L1 * Fs[1][c] + L2 * Fs[2][c] + L3 * Fs[3][c];
      const float sh = L0 * Fh[0][c] + L1 * Fh[1][c] + L2 * Fh[2][c] + L3 * Fh[3][c];
      o[c] = siluf(xn * (1.0f + sc) + sh);
    }
    ushort4 ov;
    ov.x = f2bf(o[0]);
    ov.y = f2bf(o[1]);
    ov.z = f2bf(o[2]);
    ov.w = f2bf(o[3]);
    *(ushort4*)&buf[row * 1024 + col] = ov;
  }
}

// ---------------------------------------------------------------------------
extern "C" void kernel_launch(void* const* d_in, const int* in_sizes, int n_in,
                              void* d_out, int out_size, void* d_ws, size_t ws_size,
                              hipStream_t stream) {
  (void)in_sizes; (void)n_in; (void)out_size;
  const float* gt   = (const float*)d_in[0];
  const float* noise= (const float*)d_in[1];
  const float* t    = (const float*)d_in[2];
  const float* Wt1  = (const float*)d_in[3];
  const float* bt1  = (const float*)d_in[4];
  const float* Wt2  = (const float*)d_in[5];
  const float* bt2  = (const float*)d_in[6];
  const float* W1   = (const float*)d_in[7];
  const float* b1   = (const float*)d_in[8];
  const float* W2   = (const float*)d_in[9];
  const float* b2   = (const float*)d_in[10];
  const float* W3   = (const float*)d_in[11];
  const float* b3   = (const float*)d_in[12];
  const float* g1   = (const float*)d_in[13];
  const float* be1  = (const float*)d_in[14];
  const float* Ws1  = (const float*)d_in[15];
  const float* bs1  = (const float*)d_in[16];
  const float* g2   = (const float*)d_in[17];
  const float* be2  = (const float*)d_in[18];
  const float* Ws2  = (const float*)d_in[19];
  const float* bs2  = (const float*)d_in[20];
  const float* g3   = (const float*)d_in[21];
  const float* be3  = (const float*)d_in[22];
  const float* Ws3  = (const float*)d_in[23];
  const float* bs3  = (const float*)d_in[24];
  const float* Wgt  = (const float*)d_in[25];
  const float* bgt  = (const float*)d_in[26];
  const float* Wn   = (const float*)d_in[27];
  const float* bn   = (const float*)d_in[28];

  // ---- persistent region (weights + tables), ~4.5 MB ----
  char* ws = (char*)d_ws;
  float* te2n = (float*)ws; ws += (size_t)4 * EDIM * 4;
  float* Ff   = (float*)ws; ws += (size_t)3 * 4 * 2048 * 4;
  u16* wt1    = (u16*)ws;  ws += (size_t)HDIM * DDIM * 2;
  u16* wt2    = (u16*)ws;  ws += (size_t)HDIM * HDIM * 2;
  u16* wt3    = (u16*)ws;  ws += (size_t)HDIM * HDIM * 2;
  u16* wtf    = (u16*)ws;  ws += (size_t)128 * HDIM * 2;
  const size_t persist = (size_t)(ws - (char*)d_ws);

  // ---- chunk sizing: bufA 2048 + bufB 2048 + sp 128 + st 32 = 4256 B/row ----
  const size_t avail = (ws_size > persist) ? (ws_size - persist) : 0;
  long Rmax = (long)(avail / 4256);
  Rmax = (Rmax / 2048) * 2048;
  if (Rmax > NB) Rmax = NB;
  if (Rmax < 2048) Rmax = 2048;
  long nch = (NB + Rmax - 1) / Rmax;
  long Rbal = ((NB / nch + 2047) / 2048) * 2048;
  if (Rbal > Rmax) Rbal = Rmax;

  u16* bufA = (u16*)ws;  ws += (size_t)Rbal * HDIM * 2;
  u16* bufB = (u16*)ws;  ws += (size_t)Rbal * HDIM * 2;
  float* sp = (float*)ws; ws += (size_t)Rbal * 32 * 4;
  float* st = (float*)ws;

  float* out0 = (float*)d_out;
  float* out1 = out0 + (size_t)NB * DDIM;

  // ---- one-time setup ----
  convtrans<<<dim3(HDIM / 32, DDIM / 32), 256, 0, stream>>>(W1, wt1, DDIM, HDIM);
  convtrans<<<dim3(HDIM / 32, HDIM / 32), 256, 0, stream>>>(W2, wt2, HDIM, HDIM);
  convtrans<<<dim3(HDIM / 32, HDIM / 32), 256, 0, stream>>>(W3, wt3, HDIM, HDIM);
  convtrans<<<dim3(DDIM / 32, HDIM / 32), 256, 0, stream>>>(Wgt, wtf, HDIM, DDIM);
  convtrans<<<dim3(DDIM / 32, HDIM / 32), 256, 0, stream>>>(Wn, wtf + (size_t)64 * HDIM, HDIM, DDIM);
  te_nodes<<<4, 256, 0, stream>>>(Wt1, bt1, Wt2, bt2, te2n);
  ss_nodes<<<dim3(8, 4, 3), 256, 0, stream>>>(te2n, Ws1, bs1, Ws2, bs2, Ws3, bs3, Ff);

  // ---- chunked pipeline (ping-pong bufA/bufB, in-place LN) ----
  for (long row0 = 0; row0 < NB; row0 += Rbal) {
    const long R = (NB - row0 < Rbal) ? (NB - row0) : Rbal;
    const int MT = (int)(R / 128);
    const int MT256 = (int)(R / 256);
    const float* tp = t + row0;
    const int LNB = (R >= 4096) ? 4096 : (int)R;
    const int SFB = (int)(R / 256);

    // G1 (fused mix) -> bufA
    gemm_g1<<<dim3(8, MT), 256, 0, stream>>>(gt + row0 * DDIM, noise + row0 * DDIM, tp,
                                             wt1, b1, bufA, sp);
    stats_fin<<<SFB, 256, 0, stream>>>(sp, tp, st, (int)R);
    ln_apply2<<<LNB, 256, 0, stream>>>(bufA, g1, be1, Ff + 0 * 8192, st, (int)R);

    // G2: bufA -> bufB
    gemm16<<<dim3(4, MT256), 1024, 0, stream>>>(bufA, wt2, b2, bufB, sp);
    stats_fin<<<SFB, 256, 0, stream>>>(sp, tp, st, (int)R);
    ln_apply2<<<LNB, 256, 0, stream>>>(bufB, g2, be2, Ff + 1 * 8192, st, (int)R);

    // G3: bufB -> bufA
    gemm16<<<dim3(4, MT256), 1024, 0, stream>>>(bufB, wt3, b3, bufA, sp);
    stats_fin<<<SFB, 256, 0, stream>>>(sp, tp, st, (int)R);
    ln_apply2<<<LNB, 256, 0, stream>>>(bufA, g3, be3, Ff + 2 * 8192, st, (int)R);

    // final: bufA -> out
    gemm_fin<<<dim3(1, MT), 256, 0, stream>>>(bufA, wtf, HDIM, bgt, bn,
                                              out0 + row0 * DDIM, out1 + row0 * DDIM);
  }
}

// Round 12
// 654.448 us; speedup vs baseline: 1.1265x; 1.1265x over previous
//
#include <hip/hip_runtime.h>
#include <stdint.h>

typedef unsigned short u16;
typedef __attribute__((ext_vector_type(8))) short bf16x8;
typedef __attribute__((ext_vector_type(4))) float f32x4;

#define NB    65536
#define DDIM  64
#define HDIM  1024
#define EDIM  1024

__device__ __forceinline__ float bf2f(u16 u) {
  return __uint_as_float(((unsigned)u) << 16);
}
__device__ __forceinline__ u16 f2bf(float f) {
  unsigned u = __float_as_uint(f);
  unsigned r = ((u >> 16) & 1u) + 0x7FFFu;
  return (u16)((u + r) >> 16);
}
__device__ __forceinline__ float siluf(float x) { return x / (1.0f + __expf(-x)); }

#if defined(__has_builtin)
#  if __has_builtin(__builtin_amdgcn_global_load_lds)
#    define GLL_OK 1
#  endif
#endif
#ifndef GLL_OK
#  define GLL_OK 0
#endif

__device__ __forceinline__ void gll16(const void* g, void* lds_base, int lane) {
#if GLL_OK
  (void)lane;
  __builtin_amdgcn_global_load_lds((const __attribute__((address_space(1))) void*)g,
                                   (__attribute__((address_space(3))) void*)lds_base,
                                   16, 0, 0);
#else
  *(uint4*)((char*)lds_base + lane * 16) = *(const uint4*)g;
#endif
}

// ---------------------------------------------------------------------------
// fp32 -> bf16 transposed weight convert: W (K x N) -> WT (N x K)
// ---------------------------------------------------------------------------
__global__ __launch_bounds__(256) void convtrans(const float* __restrict__ W,
                                                 u16* __restrict__ WT, int K, int N) {
  __shared__ float tile[32][33];
  const int tx = threadIdx.x & 31;
  const int ty = threadIdx.x >> 5;
  const int n0 = blockIdx.x * 32;
  const int k0 = blockIdx.y * 32;
#pragma unroll
  for (int i = 0; i < 4; ++i) {
    const int k = ty + i * 8;
    tile[k][tx] = W[(long)(k0 + k) * N + n0 + tx];
  }
  __syncthreads();
#pragma unroll
  for (int i = 0; i < 4; ++i) {
    const int n = ty + i * 8;
    WT[(long)(n0 + n) * K + k0 + tx] = f2bf(tile[tx][n]);
  }
}

// ---------------------------------------------------------------------------
// te_part: K-split x i-split partial of te2 = te1 @ Wt2 at 4 Chebyshev nodes.
// Grid (16 K-chunks of 64, 4 i-chunks of 256), 256 thr.  Each block computes
// its 4x64 te1 slice in LDS, then accumulates ALL 4 nodes per Wt2 element
// (Wt2 read exactly once overall).  TP[(j*16+kc)*1024 + i].
// ---------------------------------------------------------------------------
__global__ __launch_bounds__(256) void te_part(const float* __restrict__ Wt1,
                                               const float* __restrict__ bt1,
                                               const float* __restrict__ Wt2,
                                               float* __restrict__ TP) {
  const float tn[4] = {0.96193976625564337f, 0.69134171618254492f,
                       0.30865828381745508f, 0.03806023374435663f};
  __shared__ float te1v[4][64];
  const int tid = threadIdx.x;
  const int k0 = blockIdx.x * 64;
  const int i0 = blockIdx.y * 256;
  {
    const int j = tid >> 6;
    const int k = tid & 63;
    te1v[j][k] = siluf(tn[j] * Wt1[k0 + k] + bt1[k0 + k]);
  }
  __syncthreads();
  const int i = i0 + tid;
  float a0 = 0.f, a1 = 0.f, a2 = 0.f, a3 = 0.f;
  for (int k = 0; k < 64; ++k) {
    const float w = Wt2[(long)(k0 + k) * 1024 + i];
    a0 += te1v[0][k] * w;
    a1 += te1v[1][k] * w;
    a2 += te1v[2][k] * w;
    a3 += te1v[3][k] * w;
  }
  const int kc = blockIdx.x;
  TP[(0 * 16 + kc) * 1024 + i] = a0;
  TP[(1 * 16 + kc) * 1024 + i] = a1;
  TP[(2 * 16 + kc) * 1024 + i] = a2;
  TP[(3 * 16 + kc) * 1024 + i] = a3;
}

// te_reduce: te2n[j*1024+i] = silu(sum_kc TP[(j*16+kc)*1024+i] + bt2[i])
__global__ __launch_bounds__(256) void te_reduce(const float* __restrict__ TP,
                                                 const float* __restrict__ bt2,
                                                 float* __restrict__ te2n) {
  const int g = blockIdx.x * 256 + threadIdx.x;  // 0..4095
  const int j = g >> 10;
  const int i = g & 1023;
  float s = bt2[i];
#pragma unroll
  for (int kc = 0; kc < 16; ++kc) s += TP[(j * 16 + kc) * 1024 + i];
  te2n[g] = siluf(s);
}

// ---------------------------------------------------------------------------
// ss_part: K-split x i-split partial of ss = te2 @ Ws_b at 4 nodes, 3 mats.
// Grid (8 K-chunks of 128, 8 i-chunks of 256, 3 mats), 256 thr.  All 4 nodes
// accumulated per Ws element (each Ws read exactly once).
// SPP[((b*4+j)*8 + kc)*2048 + i].
// ---------------------------------------------------------------------------
__global__ __launch_bounds__(256) void ss_part(const float* __restrict__ te2n,
                                               const float* __restrict__ Ws1,
                                               const float* __restrict__ Ws2,
                                               const float* __restrict__ Ws3,
                                               float* __restrict__ SPP) {
  __shared__ float te2v[4][128];
  const int tid = threadIdx.x;
  const int k0 = blockIdx.x * 128;
  const int i0 = blockIdx.y * 256;
  const int b = blockIdx.z;
  const float* Ws = (b == 0) ? Ws1 : (b == 1) ? Ws2 : Ws3;
#pragma unroll
  for (int p = 0; p < 2; ++p) {
    const int idx = p * 256 + tid;  // 0..511
    const int j = idx >> 7;
    const int k = idx & 127;
    te2v[j][k] = te2n[j * 1024 + k0 + k];
  }
  __syncthreads();
  const int i = i0 + tid;
  float a0 = 0.f, a1 = 0.f, a2 = 0.f, a3 = 0.f;
  for (int k = 0; k < 128; ++k) {
    const float w = Ws[(long)(k0 + k) * 2048 + i];
    a0 += te2v[0][k] * w;
    a1 += te2v[1][k] * w;
    a2 += te2v[2][k] * w;
    a3 += te2v[3][k] * w;
  }
  const int kc = blockIdx.x;
  SPP[((b * 4 + 0) * 8 + kc) * 2048 + i] = a0;
  SPP[((b * 4 + 1) * 8 + kc) * 2048 + i] = a1;
  SPP[((b * 4 + 2) * 8 + kc) * 2048 + i] = a2;
  SPP[((b * 4 + 3) * 8 + kc) * 2048 + i] = a3;
}

// ss_reduce: F[(b*4+j)*2048+i] = sum_kc SPP[...] + bs_b[i]
__global__ __launch_bounds__(256) void ss_reduce(const float* __restrict__ SPP,
                                                 const float* __restrict__ bs1,
                                                 const float* __restrict__ bs2,
                                                 const float* __restrict__ bs3,
                                                 float* __restrict__ F) {
  const int g = blockIdx.x * 256 + threadIdx.x;  // 0..24575
  const int b = g >> 13;
  const int rem = g & 8191;
  const int i = rem & 2047;
  const float* bs = (b == 0) ? bs1 : (b == 1) ? bs2 : bs3;
  float s = bs[i];
  const int base = (g >> 11) << 3;  // (b*4+j)*8
#pragma unroll
  for (int kc = 0; kc < 8; ++kc) s += SPP[(base + kc) * 2048 + i];
  F[g] = s;
}

// ---------------------------------------------------------------------------
// gemm_g1: G1 with FUSED mixed-input staging (r10, unchanged).
// ---------------------------------------------------------------------------
__global__ __launch_bounds__(256) void gemm_g1(const float* __restrict__ gt,
                                               const float* __restrict__ noise,
                                               const float* __restrict__ t,
                                               const u16* __restrict__ BT,
                                               const float* __restrict__ bias,
                                               u16* __restrict__ Cb,
                                               float* __restrict__ SP) {
  __shared__ u16 lA[128 * 64];
  __shared__ u16 lB[128 * 64];
  const int tid = threadIdx.x;
  const int lane = tid & 63;
  const int wid = tid >> 6;

  int mtile, ntile;
  if (gridDim.x == 8 && (gridDim.y & 7) == 0) {
    const int g = (int)blockIdx.x + ((int)blockIdx.y << 3);
    mtile = ((g >> 6) << 3) + (g & 7);
    ntile = (g >> 3) & 7;
  } else {
    ntile = blockIdx.x;
    mtile = blockIdx.y;
  }
  const long m0 = (long)mtile * 128;
  const int n0 = ntile * 128;
  const int wm = (wid >> 1) * 64;
  const int wn = (wid & 1) * 64;

  const int fr = lane & 15;
  const int kq = lane >> 4;

#pragma unroll
  for (int c = 0; c < 4; ++c) {
    const int u = c * 256 + tid;
    const int row = u >> 3;
    const int src = (u & 7) ^ (row & 7);
    gll16(BT + (size_t)(n0 + row) * 64 + src * 8, &lB[(c * 256 + wid * 64) * 8], lane);
  }
#pragma unroll
  for (int c = 0; c < 4; ++c) {
    const int u = c * 256 + tid;
    const int row = u >> 3;
    const int src = (u & 7) ^ (row & 7);
    const long gr = m0 + row;
    const float tv = t[gr];
    const float one_m = 1.0f - tv;
    const float4 ga = *(const float4*)&gt[gr * 64 + src * 8];
    const float4 gb = *(const float4*)&gt[gr * 64 + src * 8 + 4];
    const float4 na = *(const float4*)&noise[gr * 64 + src * 8];
    const float4 nb = *(const float4*)&noise[gr * 64 + src * 8 + 4];
    ushort4 o0, o1;
    o0.x = f2bf(tv * ga.x + one_m * na.x);
    o0.y = f2bf(tv * ga.y + one_m * na.y);
    o0.z = f2bf(tv * ga.z + one_m * na.z);
    o0.w = f2bf(tv * ga.w + one_m * na.w);
    o1.x = f2bf(tv * gb.x + one_m * nb.x);
    o1.y = f2bf(tv * gb.y + one_m * nb.y);
    o1.z = f2bf(tv * gb.z + one_m * nb.z);
    o1.w = f2bf(tv * gb.w + one_m * nb.w);
    *(ushort4*)&lA[u * 8] = o0;
    *(ushort4*)&lA[u * 8 + 4] = o1;
  }
  __syncthreads();

  f32x4 acc[4][4];
  const f32x4 z = {0.f, 0.f, 0.f, 0.f};
#pragma unroll
  for (int i = 0; i < 4; ++i)
#pragma unroll
    for (int j = 0; j < 4; ++j) acc[i][j] = z;

#pragma unroll
  for (int ks = 0; ks < 2; ++ks) {
    bf16x8 af[4], bq[4];
#pragma unroll
    for (int i = 0; i < 4; ++i) {
      const int row = wm + i * 16 + fr;
      const int slot = (ks * 4 + kq) ^ (row & 7);
      af[i] = *(const bf16x8*)&lA[row * 64 + slot * 8];
    }
#pragma unroll
    for (int j = 0; j < 4; ++j) {
      const int row = wn + j * 16 + fr;
      const int slot = (ks * 4 + kq) ^ (row & 7);
      bq[j] = *(const bf16x8*)&lB[row * 64 + slot * 8];
    }
#pragma unroll
    for (int i = 0; i < 4; ++i)
#pragma unroll
      for (int j = 0; j < 4; ++j)
        acc[i][j] =
            __builtin_amdgcn_mfma_f32_16x16x32_bf16(af[i], bq[j], acc[i][j], 0, 0, 0);
  }

  const int rr = kq * 4;
  float bj[4];
#pragma unroll
  for (int j = 0; j < 4; ++j) bj[j] = bias[n0 + wn + j * 16 + fr];
#pragma unroll
  for (int j = 0; j < 4; ++j) {
    const int gn = n0 + wn + j * 16 + fr;
#pragma unroll
    for (int i = 0; i < 4; ++i) {
      const long gm = m0 + wm + i * 16 + rr;
#pragma unroll
      for (int r = 0; r < 4; ++r) Cb[(gm + r) * 1024 + gn] = f2bf(acc[i][j][r] + bj[j]);
    }
  }
  const int slice = ntile * 2 + (wid & 1);
#pragma unroll
  for (int i = 0; i < 4; ++i) {
#pragma unroll
    for (int r = 0; r < 4; ++r) {
      float s = 0.f, q = 0.f;
#pragma unroll
      for (int j = 0; j < 4; ++j) {
        const float v = acc[i][j][r] + bj[j];
        s += v;
        q += v * v;
      }
#pragma unroll
      for (int m = 1; m < 16; m <<= 1) {
        s += __shfl_xor(s, m, 64);
        q += __shfl_xor(q, m, 64);
      }
      if (fr == 0) {
        const long row = m0 + wm + i * 16 + rr + r;
        float2 st;
        st.x = s;
        st.y = q;
        *(float2*)&SP[(row * 16 + slice) * 2] = st;
      }
    }
  }
}

// ---------------------------------------------------------------------------
// gemm8: 256x256 MFMA GEMM (N=K=1024) — r6/r10 config, byte-identical.
// ---------------------------------------------------------------------------
__global__ __launch_bounds__(512, 2) void gemm8(const u16* __restrict__ A,
                                                const u16* __restrict__ BT,
                                                const float* __restrict__ bias,
                                                u16* __restrict__ C,
                                                float* __restrict__ SP) {
  __shared__ u16 L[65536];
  const int tid = threadIdx.x;
  const int lane = tid & 63;
  const int wid = tid >> 6;

  int mtile, ntile;
  if ((gridDim.y & 7) == 0) {
    const int g = (int)blockIdx.x + ((int)blockIdx.y << 2);
    mtile = ((g >> 5) << 3) | (g & 7);
    ntile = (g >> 3) & 3;
  } else {
    ntile = blockIdx.x;
    mtile = blockIdx.y;
  }
  const long m0 = (long)mtile * 256;
  const int n0 = ntile * 256;
  const int mwoff = (wid >> 2) * 16;
  const int nwoff = (wid & 3) * 16;

  const u16* Ag = A + m0 * 1024;
  const u16* Bg = BT + (long)n0 * 1024;

  const int fr = lane & 15;
  const int kq = lane >> 4;

  auto stageA = [&](int buf, int h, int kt) {
    const int u0 = h * 1024 + tid;
    const int u1 = u0 + 512;
    const int kk = kt * 64;
    gll16(Ag + (size_t)(u0 >> 3) * 1024 + kk + (((u0 & 7) ^ ((u0 >> 3) & 7)) << 3),
          &L[buf * 16384 + (h * 1024 + wid * 64) * 8], lane);
    gll16(Ag + (size_t)(u1 >> 3) * 1024 + kk + (((u1 & 7) ^ ((u1 >> 3) & 7)) << 3),
          &L[buf * 16384 + (h * 1024 + 512 + wid * 64) * 8], lane);
  };
  auto stageB = [&](int buf, int h, int kt) {
    const int u0 = h * 1024 + tid;
    const int u1 = u0 + 512;
    const int kk = kt * 64;
    gll16(Bg + (size_t)(u0 >> 3) * 1024 + kk + (((u0 & 7) ^ ((u0 >> 3) & 7)) << 3),
          &L[32768 + buf * 16384 + (h * 1024 + wid * 64) * 8], lane);
    gll16(Bg + (size_t)(u1 >> 3) * 1024 + kk + (((u1 & 7) ^ ((u1 >> 3) & 7)) << 3),
          &L[32768 + buf * 16384 + (h * 1024 + 512 + wid * 64) * 8], lane);
  };

  f32x4 acc[8][4];
  const f32x4 z = {0.f, 0.f, 0.f, 0.f};
#pragma unroll
  for (int i = 0; i < 8; ++i)
#pragma unroll
    for (int j = 0; j < 4; ++j) acc[i][j] = z;

  bf16x8 af[8], bf[4];

#define RD_A(buf, ibase)                                                             \
  _Pragma("unroll") for (int i2 = 0; i2 < 4; ++i2) _Pragma("unroll")                 \
      for (int ks = 0; ks < 2; ++ks) {                                               \
    const int row = mwoff + (ibase + i2) * 32 + fr;                                  \
    const int slot = (ks * 4 + kq) ^ (row & 7);                                      \
    af[i2 * 2 + ks] = *(const bf16x8*)&L[(buf) * 16384 + row * 64 + slot * 8];       \
  }
#define RD_B(buf, jbase)                                                             \
  _Pragma("unroll") for (int j2 = 0; j2 < 2; ++j2) _Pragma("unroll")                 \
      for (int ks = 0; ks < 2; ++ks) {                                               \
    const int row = nwoff + (jbase + j2) * 64 + fr;                                  \
    const int slot = (ks * 4 + kq) ^ (row & 7);                                      \
    bf[j2 * 2 + ks] =                                                                \
        *(const bf16x8*)&L[32768 + (buf) * 16384 + row * 64 + slot * 8];             \
  }
#define VMW(n) asm volatile("s_waitcnt vmcnt(" #n ")" ::: "memory");
#define BARS()                             \
  asm volatile("s_barrier" ::: "memory");  \
  __builtin_amdgcn_sched_barrier(0);
#define MFMA16(ibase, jbase)                                                         \
  __builtin_amdgcn_s_setprio(1);                                                     \
  _Pragma("unroll") for (int i2 = 0; i2 < 4; ++i2) _Pragma("unroll")                 \
      for (int j2 = 0; j2 < 2; ++j2) _Pragma("unroll") for (int ks = 0; ks < 2;      \
                                                            ++ks) {                  \
    acc[ibase + i2][jbase + j2] = __builtin_amdgcn_mfma_f32_16x16x32_bf16(           \
        af[i2 * 2 + ks], bf[j2 * 2 + ks], acc[ibase + i2][jbase + j2], 0, 0, 0);     \
  }                                                                                  \
  __builtin_amdgcn_s_setprio(0);

  stageA(0, 0, 0);
  stageB(0, 0, 0);
  stageB(0, 1, 0);
  stageA(0, 1, 0);
  VMW(4)
  BARS()

  for (int kt = 0; kt < 15; ++kt) {
    const int c = kt & 1;
    const int nx = c ^ 1;
    const int kn = kt + 1;
    stageA(nx, 0, kn);
    stageB(nx, 0, kn);
    RD_A(c, 0)
    RD_B(c, 0)
    VMW(6)
    BARS()
    MFMA16(0, 0)
    stageB(nx, 1, kn);
    stageA(nx, 1, kn);
    RD_B(c, 2)
    VMW(8)
    BARS()
    MFMA16(0, 2)
    RD_A(c, 4)
    BARS()
    MFMA16(4, 2)
    RD_B(c, 0)
    VMW(4)
    BARS()
    MFMA16(4, 0)
  }
  {
    const int c = 1;
    RD_A(c, 0)
    RD_B(c, 0)
    VMW(2)
    BARS()
    MFMA16(0, 0)
    RD_B(c, 2)
    VMW(0)
    BARS()
    MFMA16(0, 2)
    RD_A(c, 4)
    BARS()
    MFMA16(4, 2)
    RD_B(c, 0)
    BARS()
    MFMA16(4, 0)
  }
#undef RD_A
#undef RD_B
#undef VMW
#undef BARS
#undef MFMA16

  float bj[4];
#pragma unroll
  for (int j = 0; j < 4; ++j) bj[j] = bias[n0 + nwoff + j * 64 + fr];
  const int slice = ntile * 4 + (wid & 3);
#pragma unroll
  for (int i = 0; i < 8; ++i) {
    const long gmb = m0 + mwoff + i * 32 + kq * 4;
#pragma unroll
    for (int j = 0; j < 4; ++j) {
      const int gn = n0 + nwoff + j * 64 + fr;
#pragma unroll
      for (int r = 0; r < 4; ++r) C[(gmb + r) * 1024 + gn] = f2bf(acc[i][j][r] + bj[j]);
    }
#pragma unroll
    for (int r = 0; r < 4; ++r) {
      float s = 0.f, q = 0.f;
#pragma unroll
      for (int j = 0; j < 4; ++j) {
        const float v = acc[i][j][r] + bj[j];
        s += v;
        q += v * v;
      }
#pragma unroll
      for (int m = 1; m < 16; m <<= 1) {
        s += __shfl_xor(s, m, 64);
        q += __shfl_xor(q, m, 64);
      }
      if (fr == 0) {
        float2 st;
        st.x = s;
        st.y = q;
        *(float2*)&SP[((gmb + r) * 16 + slice) * 2] = st;
      }
    }
  }
}

// ---------------------------------------------------------------------------
// gemm_fin: final 128-col GEMM, conflict-free swizzled (r10, unchanged).
// ---------------------------------------------------------------------------
__global__ __launch_bounds__(256) void gemm_fin(const u16* __restrict__ A,
                                                const u16* __restrict__ BT, int K,
                                                const float* __restrict__ bias0,
                                                const float* __restrict__ bias1,
                                                float* __restrict__ Cf0,
                                                float* __restrict__ Cf1) {
  __shared__ u16 lA[128 * 64];
  __shared__ u16 lB[128 * 64];
  const int tid = threadIdx.x;
  const int lane = tid & 63;
  const int wid = tid >> 6;
  const long m0 = (long)blockIdx.y * 128;
  const int n0 = 0;
  const int wm = (wid >> 1) * 64;
  const int wn = (wid & 1) * 64;

  const u16* Ab = A + m0 * K;
  const u16* Bb = BT;

  const int fr = lane & 15;
  const int kq = lane >> 4;

  f32x4 acc[4][4];
  const f32x4 z = {0.f, 0.f, 0.f, 0.f};
#pragma unroll
  for (int i = 0; i < 4; ++i)
#pragma unroll
    for (int j = 0; j < 4; ++j) acc[i][j] = z;

  for (int kk = 0; kk < K; kk += 64) {
#pragma unroll
    for (int c = 0; c < 4; ++c) {
      const int u = c * 256 + tid;
      const int row = u >> 3;
      const int src = (u & 7) ^ (row & 7);
      gll16(Ab + (size_t)row * K + kk + src * 8, &lA[(c * 256 + wid * 64) * 8], lane);
      gll16(Bb + (size_t)row * K + kk + src * 8, &lB[(c * 256 + wid * 64) * 8], lane);
    }
    __syncthreads();
#pragma unroll
    for (int ks = 0; ks < 2; ++ks) {
      bf16x8 af[4], bq[4];
#pragma unroll
      for (int i = 0; i < 4; ++i) {
        const int row = wm + i * 16 + fr;
        const int slot = (ks * 4 + kq) ^ (row & 7);
        af[i] = *(const bf16x8*)&lA[row * 64 + slot * 8];
      }
#pragma unroll
      for (int j = 0; j < 4; ++j) {
        const int row = wn + j * 16 + fr;
        const int slot = (ks * 4 + kq) ^ (row & 7);
        bq[j] = *(const bf16x8*)&lB[row * 64 + slot * 8];
      }
#pragma unroll
      for (int i = 0; i < 4; ++i)
#pragma unroll
        for (int j = 0; j < 4; ++j)
          acc[i][j] =
              __builtin_amdgcn_mfma_f32_16x16x32_bf16(af[i], bq[j], acc[i][j], 0, 0, 0);
    }
    __syncthreads();
  }

  const int rr = kq * 4;
#pragma unroll
  for (int j = 0; j < 4; ++j) {
    const int gn = n0 + wn + j * 16 + fr;
    const float bv = (gn < 64) ? bias0[gn] : bias1[gn - 64];
    float* dst = (gn < 64) ? (Cf0 + gn) : (Cf1 + (gn - 64));
#pragma unroll
    for (int i = 0; i < 4; ++i) {
      const long gm = m0 + wm + i * 16 + rr;
#pragma unroll
      for (int r = 0; r < 4; ++r) dst[(gm + r) * 64] = acc[i][j][r] + bv;
    }
  }
}

// ---------------------------------------------------------------------------
// stats_fin: SP[row][16][2] -> ST[row][8] = {mu, rstd, L0, L1, L2, L3, 0, 0}
// ---------------------------------------------------------------------------
__global__ __launch_bounds__(256) void stats_fin(const float* __restrict__ SP,
                                                 const float* __restrict__ t,
                                                 float* __restrict__ ST, int nrows) {
  const int row = blockIdx.x * 256 + threadIdx.x;
  if (row >= nrows) return;
  float S = 0.f, Q = 0.f;
#pragma unroll
  for (int i = 0; i < 16; ++i) {
    const float2 v = *(const float2*)&SP[row * 32 + i * 2];
    S += v.x;
    Q += v.y;
  }
  const float mu = S * (1.0f / 1024.0f);
  const float var = Q * (1.0f / 1024.0f) - mu * mu;
  const float rstd = rsqrtf(var + 1e-5f);
  const float tv = t[row];
  const float tn0 = 0.96193976625564337f, tn1 = 0.69134171618254492f,
              tn2 = 0.30865828381745508f, tn3 = 0.03806023374435663f;
  float4 a, b;
  a.x = mu;
  a.y = rstd;
  a.z = (tv - tn1) * (tv - tn2) * (tv - tn3) * 6.1229347f;
  a.w = (tv - tn0) * (tv - tn2) * (tv - tn3) * -14.7820730f;
  b.x = (tv - tn0) * (tv - tn1) * (tv - tn3) * 14.7820730f;
  b.y = (tv - tn0) * (tv - tn1) * (tv - tn2) * -6.1229347f;
  b.z = 0.f;
  b.w = 0.f;
  *(float4*)&ST[row * 8] = a;
  *(float4*)&ST[row * 8 + 4] = b;
}

// ---------------------------------------------------------------------------
// ln_apply2: IN-PLACE LN + adaLN modulate + silu; per-row params from ST.
// ---------------------------------------------------------------------------
__global__ __launch_bounds__(256) void ln_apply2(u16* __restrict__ buf,
                                                 const float* __restrict__ gamma,
                                                 const float* __restrict__ beta,
                                                 const float* __restrict__ Fb,  // [4][2048]
                                                 const float* __restrict__ ST,
                                                 int nrows) {
  const int tid = threadIdx.x;
  const int col = tid * 4;

  float Fs[4][4], Fh[4][4];
#pragma unroll
  for (int j = 0; j < 4; ++j)
#pragma unroll
    for (int c = 0; c < 4; ++c) {
      Fs[j][c] = Fb[j * 2048 + col + c];
      Fh[j][c] = Fb[j * 2048 + 1024 + col + c];
    }
  const float4 gv = *(const float4*)&gamma[col];
  const float4 bv = *(const float4*)&beta[col];
  const float g[4] = {gv.x, gv.y, gv.z, gv.w};
  const float be[4] = {bv.x, bv.y, bv.z, bv.w};

  for (long row = blockIdx.x; row < nrows; row += gridDim.x) {
    const float4 p0 = *(const float4*)&ST[row * 8];
    const float4 p1 = *(const float4*)&ST[row * 8 + 4];
    const float mu = p0.x, rstd = p0.y;
    const float L0 = p0.z, L1 = p0.w, L2 = p1.x, L3 = p1.y;

    const ushort4 hv = *(const ushort4*)&buf[row * 1024 + col];
    const float x[4] = {bf2f(hv.x), bf2f(hv.y), bf2f(hv.z), bf2f(hv.w)};
    float o[4];
#pragma unroll
    for (int c = 0; c < 4; ++c) {
      const float xn = (x[c] - mu) * rstd * g[c] + be[c];
      const float sc = L0 * Fs[0][c] + L1 * Fs[1][c] + L2 * Fs[2][c] + L3 * Fs[3][c];
      const float sh = L0 * Fh[0][c] + L1 * Fh[1][c] + L2 * Fh[2][c] + L3 * Fh[3][c];
      o[c] = siluf(xn * (1.0f + sc) + sh);
    }
    ushort4 ov;
    ov.x = f2bf(o[0]);
    ov.y = f2bf(o[1]);
    ov.z = f2bf(o[2]);
    ov.w = f2bf(o[3]);
    *(ushort4*)&buf[row * 1024 + col] = ov;
  }
}

// ---------------------------------------------------------------------------
extern "C" void kernel_launch(void* const* d_in, const int* in_sizes, int n_in,
                              void* d_out, int out_size, void* d_ws, size_t ws_size,
                              hipStream_t stream) {
  (void)in_sizes; (void)n_in; (void)out_size;
  const float* gt   = (const float*)d_in[0];
  const float* noise= (const float*)d_in[1];
  const float* t    = (const float*)d_in[2];
  const float* Wt1  = (const float*)d_in[3];
  const float* bt1  = (const float*)d_in[4];
  const float* Wt2  = (const float*)d_in[5];
  const float* bt2  = (const float*)d_in[6];
  const float* W1   = (const float*)d_in[7];
  const float* b1   = (const float*)d_in[8];
  const float* W2   = (const float*)d_in[9];
  const float* b2   = (const float*)d_in[10];
  const float* W3   = (const float*)d_in[11];
  const float* b3   = (const float*)d_in[12];
  const float* g1   = (const float*)d_in[13];
  const float* be1  = (const float*)d_in[14];
  const float* Ws1  = (const float*)d_in[15];
  const float* bs1  = (const float*)d_in[16];
  const float* g2   = (const float*)d_in[17];
  const float* be2  = (const float*)d_in[18];
  const float* Ws2  = (const float*)d_in[19];
  const float* bs2  = (const float*)d_in[20];
  const float* g3   = (const float*)d_in[21];
  const float* be3  = (const float*)d_in[22];
  const float* Ws3  = (const float*)d_in[23];
  const float* bs3  = (const float*)d_in[24];
  const float* Wgt  = (const float*)d_in[25];
  const float* bgt  = (const float*)d_in[26];
  const float* Wn   = (const float*)d_in[27];
  const float* bn   = (const float*)d_in[28];

  // ---- persistent region (weights + tables + t-chain partials), ~5.6 MB ----
  char* ws = (char*)d_ws;
  float* te2n = (float*)ws; ws += (size_t)4 * EDIM * 4;
  float* Ff   = (float*)ws; ws += (size_t)3 * 4 * 2048 * 4;
  float* TP   = (float*)ws; ws += (size_t)4 * 16 * 1024 * 4;    // 256 KB
  float* SPP  = (float*)ws; ws += (size_t)3 * 4 * 8 * 2048 * 4; // 768 KB
  u16* wt1    = (u16*)ws;  ws += (size_t)HDIM * DDIM * 2;
  u16* wt2    = (u16*)ws;  ws += (size_t)HDIM * HDIM * 2;
  u16* wt3    = (u16*)ws;  ws += (size_t)HDIM * HDIM * 2;
  u16* wtf    = (u16*)ws;  ws += (size_t)128 * HDIM * 2;
  const size_t persist = (size_t)(ws - (char*)d_ws);

  // ---- chunk sizing: bufA 2048 + bufB 2048 + sp 128 + st 32 = 4256 B/row ----
  const size_t avail = (ws_size > persist) ? (ws_size - persist) : 0;
  long Rmax = (long)(avail / 4256);
  Rmax = (Rmax / 2048) * 2048;
  if (Rmax > NB) Rmax = NB;
  if (Rmax < 2048) Rmax = 2048;
  long nch = (NB + Rmax - 1) / Rmax;
  long Rbal = ((NB / nch + 2047) / 2048) * 2048;
  if (Rbal > Rmax) Rbal = Rmax;

  u16* bufA = (u16*)ws;  ws += (size_t)Rbal * HDIM * 2;
  u16* bufB = (u16*)ws;  ws += (size_t)Rbal * HDIM * 2;
  float* sp = (float*)ws; ws += (size_t)Rbal * 32 * 4;
  float* st = (float*)ws;

  float* out0 = (float*)d_out;
  float* out1 = out0 + (size_t)NB * DDIM;

  // ---- one-time setup ----
  convtrans<<<dim3(HDIM / 32, DDIM / 32), 256, 0, stream>>>(W1, wt1, DDIM, HDIM);
  convtrans<<<dim3(HDIM / 32, HDIM / 32), 256, 0, stream>>>(W2, wt2, HDIM, HDIM);
  convtrans<<<dim3(HDIM / 32, HDIM / 32), 256, 0, stream>>>(W3, wt3, HDIM, HDIM);
  convtrans<<<dim3(DDIM / 32, HDIM / 32), 256, 0, stream>>>(Wgt, wtf, HDIM, DDIM);
  convtrans<<<dim3(DDIM / 32, HDIM / 32), 256, 0, stream>>>(Wn, wtf + (size_t)64 * HDIM, HDIM, DDIM);
  te_part<<<dim3(16, 4), 256, 0, stream>>>(Wt1, bt1, Wt2, TP);
  te_reduce<<<16, 256, 0, stream>>>(TP, bt2, te2n);
  ss_part<<<dim3(8, 8, 3), 256, 0, stream>>>(te2n, Ws1, Ws2, Ws3, SPP);
  ss_reduce<<<96, 256, 0, stream>>>(SPP, bs1, bs2, bs3, Ff);

  // ---- chunked pipeline (ping-pong bufA/bufB, in-place LN) ----
  for (long row0 = 0; row0 < NB; row0 += Rbal) {
    const long R = (NB - row0 < Rbal) ? (NB - row0) : Rbal;
    const int MT = (int)(R / 128);
    const int MT256 = (int)(R / 256);
    const float* tp = t + row0;
    const int LNB = (R >= 4096) ? 4096 : (int)R;
    const int SFB = (int)(R / 256);

    // G1 (fused mix) -> bufA
    gemm_g1<<<dim3(8, MT), 256, 0, stream>>>(gt + row0 * DDIM, noise + row0 * DDIM, tp,
                                             wt1, b1, bufA, sp);
    stats_fin<<<SFB, 256, 0, stream>>>(sp, tp, st, (int)R);
    ln_apply2<<<LNB, 256, 0, stream>>>(bufA, g1, be1, Ff + 0 * 8192, st, (int)R);

    // G2: bufA -> bufB
    gemm8<<<dim3(4, MT256), 512, 0, stream>>>(bufA, wt2, b2, bufB, sp);
    stats_fin<<<SFB, 256, 0, stream>>>(sp, tp, st, (int)R);
    ln_apply2<<<LNB, 256, 0, stream>>>(bufB, g2, be2, Ff + 1 * 8192, st, (int)R);

    // G3: bufB -> bufA
    gemm8<<<dim3(4, MT256), 512, 0, stream>>>(bufB, wt3, b3, bufA, sp);
    stats_fin<<<SFB, 256, 0, stream>>>(sp, tp, st, (int)R);
    ln_apply2<<<LNB, 256, 0, stream>>>(bufA, g3, be3, Ff + 2 * 8192, st, (int)R);

    // final: bufA -> out
    gemm_fin<<<dim3(1, MT), 256, 0, stream>>>(bufA, wtf, HDIM, bgt, bn,
                                              out0 + row0 * DDIM, out1 + row0 * DDIM);
  }
}